// Round 1
// baseline (865.249 us; speedup 1.0000x reference)
//
#include <hip/hip_runtime.h>

#define N_ROWS  131072   // 32*64*64
#define DIM     64
#define N_EMBED 512

// ---------- precompute ||e_j||^2 ----------
__global__ void se_kernel(const float* __restrict__ embed, float* __restrict__ se) {
    int j = blockIdx.x * blockDim.x + threadIdx.x;
    if (j >= N_EMBED) return;
    float s = 0.f;
#pragma unroll
    for (int d = 0; d < DIM; ++d) {
        float e = embed[d * N_EMBED + j];
        s = fmaf(e, e, s);
    }
    se[j] = s;
}

// ---------- main: argmin + quantize + diff + segment sums ----------
__launch_bounds__(256)
__global__ void vq_main(const float* __restrict__ input,
                        const float* __restrict__ embed,
                        const float* __restrict__ se,
                        float* __restrict__ out_q,
                        float* __restrict__ out_ind,
                        float* __restrict__ counts,
                        float* __restrict__ esum,
                        double* __restrict__ diff_acc) {
    int i = blockIdx.x * blockDim.x + threadIdx.x;   // one row per thread

    // load row into registers (16B loads)
    float row[DIM];
    const float* rp = input + (size_t)i * DIM;
#pragma unroll
    for (int d = 0; d < DIM; d += 4) {
        float4 v = *reinterpret_cast<const float4*>(rp + d);
        row[d] = v.x; row[d + 1] = v.y; row[d + 2] = v.z; row[d + 3] = v.w;
    }

    float sx = 0.f;
#pragma unroll
    for (int d = 0; d < DIM; ++d) sx = fmaf(row[d], row[d], sx);

    // argmin over 512 codes; embed addresses are wave-uniform -> scalar loads
    float bestd = INFINITY;
    int bestj = 0;
    for (int j = 0; j < N_EMBED; j += 2) {
        float a0 = 0.f, a1 = 0.f, b0 = 0.f, b1 = 0.f;
#pragma unroll
        for (int d = 0; d < DIM; d += 2) {
            a0 = fmaf(row[d],     embed[d * N_EMBED + j],           a0);
            b0 = fmaf(row[d],     embed[d * N_EMBED + j + 1],       b0);
            a1 = fmaf(row[d + 1], embed[(d + 1) * N_EMBED + j],     a1);
            b1 = fmaf(row[d + 1], embed[(d + 1) * N_EMBED + j + 1], b1);
        }
        float dA = (sx - 2.f * (a0 + a1)) + se[j];
        float dB = (sx - 2.f * (b0 + b1)) + se[j + 1];
        if (dA < bestd) { bestd = dA; bestj = j; }
        if (dB < bestd) { bestd = dB; bestj = j + 1; }
    }

    out_ind[i] = (float)bestj;
    atomicAdd(&counts[bestj], 1.0f);

    // quantize_st = x + (q - x), diff partial, embed_sum atomics
    float dsum = 0.f;
    float* oq = out_q + (size_t)i * DIM;
#pragma unroll
    for (int d = 0; d < DIM; d += 4) {
        float4 o;
        float q0 = embed[(d + 0) * N_EMBED + bestj];
        float q1 = embed[(d + 1) * N_EMBED + bestj];
        float q2 = embed[(d + 2) * N_EMBED + bestj];
        float q3 = embed[(d + 3) * N_EMBED + bestj];
        float t0 = q0 - row[d + 0];
        float t1 = q1 - row[d + 1];
        float t2 = q2 - row[d + 2];
        float t3 = q3 - row[d + 3];
        o.x = row[d + 0] + t0;
        o.y = row[d + 1] + t1;
        o.z = row[d + 2] + t2;
        o.w = row[d + 3] + t3;
        *reinterpret_cast<float4*>(oq + d) = o;
        dsum = fmaf(t0, t0, dsum);
        dsum = fmaf(t1, t1, dsum);
        dsum = fmaf(t2, t2, dsum);
        dsum = fmaf(t3, t3, dsum);
        atomicAdd(&esum[(d + 0) * N_EMBED + bestj], row[d + 0]);
        atomicAdd(&esum[(d + 1) * N_EMBED + bestj], row[d + 1]);
        atomicAdd(&esum[(d + 2) * N_EMBED + bestj], row[d + 2]);
        atomicAdd(&esum[(d + 3) * N_EMBED + bestj], row[d + 3]);
    }

    // wave -> block reduction of diff, one f64 atomic per block
    for (int off = 32; off > 0; off >>= 1) dsum += __shfl_down(dsum, off, 64);
    __shared__ float wsum[4];
    int lane = threadIdx.x & 63, wid = threadIdx.x >> 6;
    if (lane == 0) wsum[wid] = dsum;
    __syncthreads();
    if (threadIdx.x == 0) {
        float b = wsum[0] + wsum[1] + wsum[2] + wsum[3];
        atomicAdd(diff_acc, (double)b);
    }
}

// ---------- finalize: EMA update + normalization + diff scalar ----------
__global__ void vq_finalize(const float* __restrict__ cluster_size,
                            const float* __restrict__ embed_avg,
                            const float* __restrict__ counts,
                            const float* __restrict__ esum,
                            const double* __restrict__ diff_acc,
                            float* __restrict__ out_diff,
                            float* __restrict__ out_new_embed,
                            float* __restrict__ out_ncs,
                            float* __restrict__ out_nea) {
    int t = threadIdx.x;  // 512 threads, 1 block
    const float DEC = 0.99f, OMD = 0.01f, EPSF = 1e-5f;

    float ncs = cluster_size[t] * DEC + OMD * counts[t];
    out_ncs[t] = ncs;

    __shared__ float red[512];
    red[t] = ncs;
    __syncthreads();
    for (int s = 256; s > 0; s >>= 1) {
        if (t < s) red[t] += red[t + s];
        __syncthreads();
    }
    float n = red[0];
    float cs = (ncs + EPSF) / (n + 512.0f * EPSF) * n;

#pragma unroll
    for (int d = 0; d < DIM; ++d) {
        float es = embed_avg[d * N_EMBED + t] * DEC + OMD * esum[d * N_EMBED + t];
        out_nea[d * N_EMBED + t] = es;
        out_new_embed[d * N_EMBED + t] = es / cs;
    }
    if (t == 0) out_diff[0] = (float)(*diff_acc * (1.0 / 8388608.0));
}

extern "C" void kernel_launch(void* const* d_in, const int* in_sizes, int n_in,
                              void* d_out, int out_size, void* d_ws, size_t ws_size,
                              hipStream_t stream) {
    const float* input        = (const float*)d_in[0];
    const float* embed        = (const float*)d_in[1];
    const float* cluster_size = (const float*)d_in[2];
    const float* embed_avg    = (const float*)d_in[3];

    float* out_q    = (float*)d_out;          // 8388608
    float* out_diff = out_q + 8388608;        // 1
    float* out_ind  = out_diff + 1;           // 131072
    float* out_ne   = out_ind + 131072;       // 32768
    float* out_ncs  = out_ne + 32768;         // 512
    float* out_nea  = out_ncs + 512;          // 32768

    char*   ws       = (char*)d_ws;
    double* diff_acc = (double*)ws;                           // 8 B
    float*  counts   = (float*)(ws + 8);                      // 512 f32
    float*  esum     = (float*)(ws + 8 + 512 * 4);            // 32768 f32
    float*  se       = (float*)(ws + 8 + 512 * 4 + 32768 * 4);// 512 f32

    hipMemsetAsync(d_ws, 0, 8 + 512 * 4 + 32768 * 4, stream);
    se_kernel<<<2, 256, 0, stream>>>(embed, se);
    vq_main<<<512, 256, 0, stream>>>(input, embed, se, out_q, out_ind, counts, esum, diff_acc);
    vq_finalize<<<1, 512, 0, stream>>>(cluster_size, embed_avg, counts, esum, diff_acc,
                                       out_diff, out_ne, out_ncs, out_nea);
}

// Round 2
// 486.453 us; speedup vs baseline: 1.7787x; 1.7787x over previous
//
#include <hip/hip_runtime.h>

#define DIM     64
#define N_EMBED 512
#define N_ROWS  131072   // 32*64*64

// ---------- precompute ||e_j||^2 (identical arithmetic to round 1) ----------
__global__ void se_kernel(const float* __restrict__ embed, float* __restrict__ se) {
    int j = blockIdx.x * blockDim.x + threadIdx.x;
    if (j >= N_EMBED) return;
    float s = 0.f;
#pragma unroll
    for (int d = 0; d < DIM; ++d) {
        float e = embed[d * N_EMBED + j];
        s = fmaf(e, e, s);
    }
    se[j] = s;
}

// ---------- assign: argmin over codes, 4 waves/block each take 128 codes ----------
__launch_bounds__(256)
__global__ void vq_assign(const float* __restrict__ input,
                          const float* __restrict__ embed,
                          const float* __restrict__ se,
                          float* __restrict__ out_ind,
                          int*   __restrict__ ind,
                          float* __restrict__ counts) {
    const int lane = threadIdx.x & 63;
    const int wid  = threadIdx.x >> 6;                       // 0..3
    const int row  = blockIdx.x * 64 + lane;                 // all 4 waves: same 64 rows
    const int jbase = __builtin_amdgcn_readfirstlane(wid) * 128;  // wave-uniform -> scalar loads

    // load row into registers
    float rowv[DIM];
    const float* rp = input + (size_t)row * DIM;
#pragma unroll
    for (int d = 0; d < DIM; d += 4) {
        float4 v = *reinterpret_cast<const float4*>(rp + d);
        rowv[d] = v.x; rowv[d + 1] = v.y; rowv[d + 2] = v.z; rowv[d + 3] = v.w;
    }
    float sx = 0.f;
#pragma unroll
    for (int d = 0; d < DIM; ++d) sx = fmaf(rowv[d], rowv[d], sx);

    // local argmin over this wave's 128 codes (same fma chains as round 1)
    float bestd = INFINITY;
    int bestj = 0;
    for (int j0 = 0; j0 < 128; j0 += 2) {
        const int j = jbase + j0;
        float a0 = 0.f, a1 = 0.f, b0 = 0.f, b1 = 0.f;
#pragma unroll
        for (int d = 0; d < DIM; d += 2) {
            a0 = fmaf(rowv[d],     embed[d * N_EMBED + j],           a0);
            b0 = fmaf(rowv[d],     embed[d * N_EMBED + j + 1],       b0);
            a1 = fmaf(rowv[d + 1], embed[(d + 1) * N_EMBED + j],     a1);
            b1 = fmaf(rowv[d + 1], embed[(d + 1) * N_EMBED + j + 1], b1);
        }
        float dA = (sx - 2.f * (a0 + a1)) + se[j];
        float dB = (sx - 2.f * (b0 + b1)) + se[j + 1];
        if (dA < bestd) { bestd = dA; bestj = j; }
        if (dB < bestd) { bestd = dB; bestj = j + 1; }
    }

    // cross-wave reduce: strict < with increasing wave order == first-index-wins
    __shared__ float sdist[4][64];
    __shared__ int   sjj[4][64];
    sdist[wid][lane] = bestd;
    sjj[wid][lane]   = bestj;
    __syncthreads();
    if (threadIdx.x < 64) {
        float bd = sdist[0][lane];
        int   bj = sjj[0][lane];
#pragma unroll
        for (int w = 1; w < 4; ++w) {
            float dw = sdist[w][lane];
            int   jw = sjj[w][lane];
            if (dw < bd) { bd = dw; bj = jw; }
        }
        int r = blockIdx.x * 64 + lane;
        out_ind[r] = (float)bj;
        ind[r]     = bj;
        atomicAdd(&counts[bj], 1.0f);
    }
}

// ---------- scatter: per-block LDS segment-sum, flush plain stores to partials ----------
__launch_bounds__(256)
__global__ void vq_scatter(const float* __restrict__ input,
                           const int* __restrict__ ind,
                           float* __restrict__ partials) {
    __shared__ float lesum[DIM * N_EMBED];   // 128 KB
    for (int k = threadIdx.x; k < DIM * N_EMBED; k += 256) lesum[k] = 0.f;
    __syncthreads();

    const int base = blockIdx.x * 512;       // 512 rows per block
#pragma unroll
    for (int rr = 0; rr < 2; ++rr) {
        const int row = base + rr * 256 + threadIdx.x;
        const int j = ind[row];
        const float* rp = input + (size_t)row * DIM;
#pragma unroll
        for (int d = 0; d < DIM; d += 4) {
            float4 v = *reinterpret_cast<const float4*>(rp + d);
            atomicAdd(&lesum[(d + 0) * N_EMBED + j], v.x);
            atomicAdd(&lesum[(d + 1) * N_EMBED + j], v.y);
            atomicAdd(&lesum[(d + 2) * N_EMBED + j], v.z);
            atomicAdd(&lesum[(d + 3) * N_EMBED + j], v.w);
        }
    }
    __syncthreads();

    float* dst = partials + (size_t)blockIdx.x * (DIM * N_EMBED);
    for (int k = threadIdx.x * 4; k < DIM * N_EMBED; k += 1024) {
        float4 v = *reinterpret_cast<float4*>(&lesum[k]);
        *reinterpret_cast<float4*>(dst + k) = v;
    }
}

// ---------- reduce the 256 per-block partials -> esum ----------
__global__ void vq_reduce(const float* __restrict__ partials, float* __restrict__ esum) {
    int e = blockIdx.x * blockDim.x + threadIdx.x;   // 32768 threads
    if (e >= DIM * N_EMBED) return;
    float s = 0.f;
#pragma unroll 8
    for (int p = 0; p < 256; ++p) s += partials[(size_t)p * (DIM * N_EMBED) + e];
    esum[e] = s;
}

// ---------- quantize + diff (round-1 arithmetic) ----------
__launch_bounds__(256)
__global__ void vq_quantize(const float* __restrict__ input,
                            const float* __restrict__ embed,
                            const int* __restrict__ ind,
                            float* __restrict__ out_q,
                            double* __restrict__ diff_acc) {
    int i = blockIdx.x * blockDim.x + threadIdx.x;
    const int bestj = ind[i];
    const float* rp = input + (size_t)i * DIM;
    float* oq = out_q + (size_t)i * DIM;
    float dsum = 0.f;
#pragma unroll
    for (int d = 0; d < DIM; d += 4) {
        float4 v = *reinterpret_cast<const float4*>(rp + d);
        float q0 = embed[(d + 0) * N_EMBED + bestj];
        float q1 = embed[(d + 1) * N_EMBED + bestj];
        float q2 = embed[(d + 2) * N_EMBED + bestj];
        float q3 = embed[(d + 3) * N_EMBED + bestj];
        float t0 = q0 - v.x;
        float t1 = q1 - v.y;
        float t2 = q2 - v.z;
        float t3 = q3 - v.w;
        float4 o;
        o.x = v.x + t0; o.y = v.y + t1; o.z = v.z + t2; o.w = v.w + t3;
        *reinterpret_cast<float4*>(oq + d) = o;
        dsum = fmaf(t0, t0, dsum);
        dsum = fmaf(t1, t1, dsum);
        dsum = fmaf(t2, t2, dsum);
        dsum = fmaf(t3, t3, dsum);
    }
    for (int off = 32; off > 0; off >>= 1) dsum += __shfl_down(dsum, off, 64);
    __shared__ float wsum[4];
    int lane = threadIdx.x & 63, wid = threadIdx.x >> 6;
    if (lane == 0) wsum[wid] = dsum;
    __syncthreads();
    if (threadIdx.x == 0) {
        float b = wsum[0] + wsum[1] + wsum[2] + wsum[3];
        atomicAdd(diff_acc, (double)b);
    }
}

// ---------- finalize: EMA update + normalization + diff scalar ----------
__global__ void vq_finalize(const float* __restrict__ cluster_size,
                            const float* __restrict__ embed_avg,
                            const float* __restrict__ counts,
                            const float* __restrict__ esum,
                            const double* __restrict__ diff_acc,
                            float* __restrict__ out_diff,
                            float* __restrict__ out_new_embed,
                            float* __restrict__ out_ncs,
                            float* __restrict__ out_nea) {
    int t = threadIdx.x;  // 512 threads, 1 block
    const float DEC = 0.99f, OMD = 0.01f, EPSF = 1e-5f;

    float ncs = cluster_size[t] * DEC + OMD * counts[t];
    out_ncs[t] = ncs;

    __shared__ float red[512];
    red[t] = ncs;
    __syncthreads();
    for (int s = 256; s > 0; s >>= 1) {
        if (t < s) red[t] += red[t + s];
        __syncthreads();
    }
    float n = red[0];
    float cs = (ncs + EPSF) / (n + 512.0f * EPSF) * n;

#pragma unroll
    for (int d = 0; d < DIM; ++d) {
        float es = embed_avg[d * N_EMBED + t] * DEC + OMD * esum[d * N_EMBED + t];
        out_nea[d * N_EMBED + t] = es;
        out_new_embed[d * N_EMBED + t] = es / cs;
    }
    if (t == 0) out_diff[0] = (float)(*diff_acc * (1.0 / 8388608.0));
}

extern "C" void kernel_launch(void* const* d_in, const int* in_sizes, int n_in,
                              void* d_out, int out_size, void* d_ws, size_t ws_size,
                              hipStream_t stream) {
    const float* input        = (const float*)d_in[0];
    const float* embed        = (const float*)d_in[1];
    const float* cluster_size = (const float*)d_in[2];
    const float* embed_avg    = (const float*)d_in[3];

    float* out_q    = (float*)d_out;          // 8388608 floats
    float* out_diff = out_q + 8388608;        // 1
    float* out_ind  = out_diff + 1;           // 131072
    float* out_ne   = out_ind + 131072;       // 32768
    float* out_ncs  = out_ne + 32768;         // 512
    float* out_nea  = out_ncs + 512;          // 32768

    // ws layout (~660 KB total)
    char*   ws       = (char*)d_ws;
    double* diff_acc = (double*)ws;                        // [0,8)
    float*  counts   = (float*)(ws + 256);                 // 512 f32
    float*  se       = (float*)(ws + 4096);                // 512 f32
    int*    ind      = (int*)(ws + 8192);                  // 131072 i32
    float*  esum     = (float*)(ws + 8192 + 524288);       // 32768 f32

    // partials live in the out_q region (exactly 256*32768 floats),
    // consumed by vq_reduce BEFORE vq_quantize overwrites it.
    float* partials = out_q;

    hipMemsetAsync(d_ws, 0, 4096, stream);  // zero diff_acc + counts
    se_kernel<<<2, 256, 0, stream>>>(embed, se);
    vq_assign<<<2048, 256, 0, stream>>>(input, embed, se, out_ind, ind, counts);
    vq_scatter<<<256, 256, 0, stream>>>(input, ind, partials);
    vq_reduce<<<128, 256, 0, stream>>>(partials, esum);
    vq_quantize<<<512, 256, 0, stream>>>(input, embed, ind, out_q, diff_acc);
    vq_finalize<<<1, 512, 0, stream>>>(cluster_size, embed_avg, counts, esum, diff_acc,
                                       out_diff, out_ne, out_ncs, out_nea);
}

// Round 3
// 286.319 us; speedup vs baseline: 3.0220x; 1.6990x over previous
//
#include <hip/hip_runtime.h>

#define DIM     64
#define N_EMBED 512
#define N_ROWS  131072   // 32*64*64
#define XPAD    132      // 128 + 4 pad (bank-conflict break)

// ---------- precompute ||e_j||^2 ----------
__global__ void se_kernel(const float* __restrict__ embed, float* __restrict__ se) {
    int j = blockIdx.x * blockDim.x + threadIdx.x;
    if (j >= N_EMBED) return;
    float s = 0.f;
#pragma unroll
    for (int d = 0; d < DIM; ++d) {
        float e = embed[d * N_EMBED + j];
        s = fmaf(e, e, s);
    }
    se[j] = s;
}

// ---------- assign: LDS-tiled fp32 GEMM-argmin ----------
// block = 256 threads, M_TILE = 128 rows, N chunks of 128 codes, K = 64.
// thread (tr,tc) owns an 8-row x 8-col micro-tile.
__launch_bounds__(256, 2)
__global__ void vq_assign(const float* __restrict__ input,
                          const float* __restrict__ embed,
                          const float* __restrict__ se,
                          float* __restrict__ out_ind,
                          int*   __restrict__ ind) {
    __shared__ float Xs[64][XPAD];   // [k][row]   33.8 KB
    __shared__ float Es[64][XPAD];   // [k][col]   33.8 KB (reused for final reduce)
    __shared__ float sxs[128];

    const int t    = threadIdx.x;
    const int row0 = blockIdx.x * 128;
    const int tr   = t >> 4;   // 0..15
    const int tc   = t & 15;   // 0..15

    // ---- stage X transposed: Xs[k][i] = input[(row0+i)*64 + k] ----
#pragma unroll
    for (int ph = 0; ph < 8; ++ph) {
        int idx = ph * 256 + t;      // 0..2047
        int row = idx >> 4;          // 0..127
        int kq  = idx & 15;          // 0..15
        float4 v = *reinterpret_cast<const float4*>(
            &input[(size_t)(row0 + row) * 64 + kq * 4]);
        Xs[kq * 4 + 0][row] = v.x;
        Xs[kq * 4 + 1][row] = v.y;
        Xs[kq * 4 + 2][row] = v.z;
        Xs[kq * 4 + 3][row] = v.w;
    }
    __syncthreads();

    // ---- sx per row ----
    if (t < 128) {
        float s = 0.f;
#pragma unroll 8
        for (int k = 0; k < 64; ++k) { float x = Xs[k][t]; s = fmaf(x, x, s); }
        sxs[t] = s;
    }

    float bestd[8], sx[8];
    int   bestj[8];
#pragma unroll
    for (int r = 0; r < 8; ++r) { bestd[r] = INFINITY; bestj[r] = 0; }

    for (int chunk = 0; chunk < 4; ++chunk) {
        const int ccb = chunk * 128;
        __syncthreads();   // prev k-loop done reading Es (also fences sxs/Xs)
#pragma unroll
        for (int ph = 0; ph < 8; ++ph) {
            int idx = ph * 256 + t;  // 0..2047
            int k   = idx >> 5;      // 0..63
            int cq  = idx & 31;      // 0..31
            float4 v = *reinterpret_cast<const float4*>(
                &embed[k * N_EMBED + ccb + cq * 4]);
            *reinterpret_cast<float4*>(&Es[k][cq * 4]) = v;
        }
        __syncthreads();
        if (chunk == 0) {
#pragma unroll
            for (int r = 0; r < 8; ++r) sx[r] = sxs[tr * 8 + r];
        }

        float acc[8][8];
#pragma unroll
        for (int r = 0; r < 8; ++r)
#pragma unroll
            for (int c = 0; c < 8; ++c) acc[r][c] = 0.f;

#pragma unroll 2
        for (int k = 0; k < 64; ++k) {
            float a[8], b[8];
            *reinterpret_cast<float4*>(&a[0]) = *reinterpret_cast<const float4*>(&Xs[k][tr * 8]);
            *reinterpret_cast<float4*>(&a[4]) = *reinterpret_cast<const float4*>(&Xs[k][tr * 8 + 4]);
            *reinterpret_cast<float4*>(&b[0]) = *reinterpret_cast<const float4*>(&Es[k][tc * 8]);
            *reinterpret_cast<float4*>(&b[4]) = *reinterpret_cast<const float4*>(&Es[k][tc * 8 + 4]);
#pragma unroll
            for (int r = 0; r < 8; ++r)
#pragma unroll
                for (int c = 0; c < 8; ++c)
                    acc[r][c] = fmaf(a[r], b[c], acc[r][c]);
        }

        // finalize this chunk: scan cols in increasing j (first-wins ties)
#pragma unroll
        for (int c = 0; c < 8; ++c) {
            int j = ccb + tc * 8 + c;
            float sej = se[j];
#pragma unroll
            for (int r = 0; r < 8; ++r) {
                float d = (sx[r] - 2.f * acc[r][c]) + sej;
                if (d < bestd[r]) { bestd[r] = d; bestj[r] = j; }
            }
        }
    }

    // ---- cross-thread argmin reduce (lexicographic (d, j) == global first-min) ----
    __syncthreads();
    float* rd = &Es[0][0];                 // [128][17]
    int*   rj = (int*)(rd + 128 * 17);     // [128][17]
#pragma unroll
    for (int r = 0; r < 8; ++r) {
        rd[(tr * 8 + r) * 17 + tc] = bestd[r];
        rj[(tr * 8 + r) * 17 + tc] = bestj[r];
    }
    __syncthreads();
    if (t < 128) {
        float bd = rd[t * 17 + 0];
        int   bj = rj[t * 17 + 0];
#pragma unroll
        for (int w = 1; w < 16; ++w) {
            float dw = rd[t * 17 + w];
            int   jw = rj[t * 17 + w];
            if (dw < bd || (dw == bd && jw < bj)) { bd = dw; bj = jw; }
        }
        out_ind[row0 + t] = (float)bj;
        ind[row0 + t]     = bj;
    }
}

// ---------- post: fused quantize + diff + segment-sum (LDS) + atomic flush ----------
__launch_bounds__(256, 1)
__global__ void vq_post(const float* __restrict__ input,
                        const float* __restrict__ embed,
                        const int* __restrict__ ind,
                        float* __restrict__ out_q,
                        float* __restrict__ esum,
                        float* __restrict__ counts,
                        double* __restrict__ diff_acc) {
    __shared__ float lesum[DIM * N_EMBED];   // 128 KB
    __shared__ float lcount[N_EMBED];
    __shared__ float wsum[4];
    const int t = threadIdx.x;

    float4* l4 = reinterpret_cast<float4*>(lesum);
#pragma unroll
    for (int i = 0; i < 32; ++i) l4[t + i * 256] = float4{0.f, 0.f, 0.f, 0.f};
    lcount[t] = 0.f;
    lcount[t + 256] = 0.f;
    __syncthreads();

    float dsum = 0.f;
#pragma unroll
    for (int rr = 0; rr < 2; ++rr) {
        const int row = blockIdx.x * 512 + rr * 256 + t;
        const int j = ind[row];
        atomicAdd(&lcount[j], 1.0f);
        const float* rp = input + (size_t)row * DIM;
        float* oq = out_q + (size_t)row * DIM;
#pragma unroll
        for (int d = 0; d < DIM; d += 4) {
            float4 v = *reinterpret_cast<const float4*>(rp + d);
            float q0 = embed[(d + 0) * N_EMBED + j];
            float q1 = embed[(d + 1) * N_EMBED + j];
            float q2 = embed[(d + 2) * N_EMBED + j];
            float q3 = embed[(d + 3) * N_EMBED + j];
            float t0 = q0 - v.x;
            float t1 = q1 - v.y;
            float t2 = q2 - v.z;
            float t3 = q3 - v.w;
            float4 o;
            o.x = v.x + t0; o.y = v.y + t1; o.z = v.z + t2; o.w = v.w + t3;
            *reinterpret_cast<float4*>(oq + d) = o;
            dsum = fmaf(t0, t0, dsum);
            dsum = fmaf(t1, t1, dsum);
            dsum = fmaf(t2, t2, dsum);
            dsum = fmaf(t3, t3, dsum);
            atomicAdd(&lesum[(d + 0) * N_EMBED + j], v.x);
            atomicAdd(&lesum[(d + 1) * N_EMBED + j], v.y);
            atomicAdd(&lesum[(d + 2) * N_EMBED + j], v.z);
            atomicAdd(&lesum[(d + 3) * N_EMBED + j], v.w);
        }
    }
    __syncthreads();

    // coalesced atomic flush into global esum / counts
    for (int i = t; i < DIM * N_EMBED; i += 256) {
        float v = lesum[i];
        if (v != 0.f) atomicAdd(&esum[i], v);
    }
    for (int c = t; c < N_EMBED; c += 256) {
        float v = lcount[c];
        if (v != 0.f) atomicAdd(&counts[c], v);
    }

    // diff: wave -> block reduce, one f64 atomic per block
    for (int off = 32; off > 0; off >>= 1) dsum += __shfl_down(dsum, off, 64);
    int lane = t & 63, wid = t >> 6;
    if (lane == 0) wsum[wid] = dsum;
    __syncthreads();
    if (t == 0) {
        float b = wsum[0] + wsum[1] + wsum[2] + wsum[3];
        atomicAdd(diff_acc, (double)b);
    }
}

// ---------- finalize ----------
__global__ void vq_finalize(const float* __restrict__ cluster_size,
                            const float* __restrict__ embed_avg,
                            const float* __restrict__ counts,
                            const float* __restrict__ esum,
                            const double* __restrict__ diff_acc,
                            float* __restrict__ out_diff,
                            float* __restrict__ out_new_embed,
                            float* __restrict__ out_ncs,
                            float* __restrict__ out_nea) {
    int t = threadIdx.x;  // 512 threads, 1 block
    const float DEC = 0.99f, OMD = 0.01f, EPSF = 1e-5f;

    float ncs = cluster_size[t] * DEC + OMD * counts[t];
    out_ncs[t] = ncs;

    __shared__ float red[512];
    red[t] = ncs;
    __syncthreads();
    for (int s = 256; s > 0; s >>= 1) {
        if (t < s) red[t] += red[t + s];
        __syncthreads();
    }
    float n = red[0];
    float cs = (ncs + EPSF) / (n + 512.0f * EPSF) * n;

#pragma unroll
    for (int d = 0; d < DIM; ++d) {
        float es = embed_avg[d * N_EMBED + t] * DEC + OMD * esum[d * N_EMBED + t];
        out_nea[d * N_EMBED + t] = es;
        out_new_embed[d * N_EMBED + t] = es / cs;
    }
    if (t == 0) out_diff[0] = (float)(*diff_acc * (1.0 / 8388608.0));
}

extern "C" void kernel_launch(void* const* d_in, const int* in_sizes, int n_in,
                              void* d_out, int out_size, void* d_ws, size_t ws_size,
                              hipStream_t stream) {
    const float* input        = (const float*)d_in[0];
    const float* embed        = (const float*)d_in[1];
    const float* cluster_size = (const float*)d_in[2];
    const float* embed_avg    = (const float*)d_in[3];

    float* out_q    = (float*)d_out;          // 8388608 floats
    float* out_diff = out_q + 8388608;        // 1
    float* out_ind  = out_diff + 1;           // 131072
    float* out_ne   = out_ind + 131072;       // 32768
    float* out_ncs  = out_ne + 32768;         // 512
    float* out_nea  = out_ncs + 512;          // 32768

    // ws layout (~650 KB total)
    char*   ws       = (char*)d_ws;
    double* diff_acc = (double*)ws;                        // [0,8)
    float*  counts   = (float*)(ws + 256);                 // 512 f32
    float*  se       = (float*)(ws + 4096);                // 512 f32
    int*    ind      = (int*)(ws + 8192);                  // 131072 i32
    float*  esum     = (float*)(ws + 8192 + 524288);       // 32768 f32

    hipMemsetAsync(ws, 0, 4096, stream);                   // diff_acc + counts
    hipMemsetAsync(ws + 8192 + 524288, 0, 131072, stream); // esum
    se_kernel<<<2, 256, 0, stream>>>(embed, se);
    vq_assign<<<1024, 256, 0, stream>>>(input, embed, se, out_ind, ind);
    vq_post<<<256, 256, 0, stream>>>(input, embed, ind, out_q, esum, counts, diff_acc);
    vq_finalize<<<1, 512, 0, stream>>>(cluster_size, embed_avg, counts, esum, diff_acc,
                                       out_diff, out_ne, out_ncs, out_nea);
}

// Round 6
// 280.668 us; speedup vs baseline: 3.0828x; 1.0201x over previous
//
#include <hip/hip_runtime.h>

#define DIM     64
#define N_EMBED 512
#define N_ROWS  131072   // 32*64*64
#define XPAD    132      // row pitch (bank stagger); swizzle stays within [0,128)

// ---------- prep: ||e_j||^2 and (optional) embed transpose ----------
__global__ void prep_kernel(const float* __restrict__ embed,
                            float* __restrict__ se,
                            float* __restrict__ embed_t,
                            int do_et) {
    int j = blockIdx.x * blockDim.x + threadIdx.x;   // 0..511
    if (j >= N_EMBED) return;
    float s = 0.f;
#pragma unroll
    for (int d = 0; d < DIM; d += 4) {
        float b0 = embed[(d + 0) * N_EMBED + j];
        float b1 = embed[(d + 1) * N_EMBED + j];
        float b2 = embed[(d + 2) * N_EMBED + j];
        float b3 = embed[(d + 3) * N_EMBED + j];
        s = fmaf(b0, b0, s); s = fmaf(b1, b1, s);
        s = fmaf(b2, b2, s); s = fmaf(b3, b3, s);
        if (do_et) {
            float4 v; v.x = b0; v.y = b1; v.z = b2; v.w = b3;
            *reinterpret_cast<float4*>(&embed_t[j * DIM + d]) = v;
        }
    }
    se[j] = s;
}

// ---------- assign: LDS-tiled fp32 GEMM-argmin, XOR-swizzled Es ----------
// Swizzle: float4 block at column c stored at slot c ^ (bit5(c)*4).
// Involution => bijective (round-4's +4 shift collided at c=60/64).
__launch_bounds__(256, 2)
__global__ void vq_assign(const float* __restrict__ input,
                          const float* __restrict__ embed,
                          const float* __restrict__ se,
                          float* __restrict__ out_ind,
                          int*   __restrict__ ind) {
    __shared__ float Xs[64][XPAD];   // [k][row]
    __shared__ float Es[64][XPAD];   // [k][swizzled col]; reused for final reduce
    __shared__ float sxs[128];

    const int t    = threadIdx.x;
    const int row0 = blockIdx.x * 128;
    const int tr   = t >> 4;   // 0..15
    const int tc   = t & 15;   // 0..15
    const int bx   = ((tc >> 2) & 1) * 4;   // bit5(tc*8) * 4, XOR on read

    // ---- stage X transposed: Xs[k][i] = input[(row0+i)*64 + k] ----
#pragma unroll
    for (int ph = 0; ph < 8; ++ph) {
        int idx = ph * 256 + t;      // 0..2047
        int row = idx >> 4;          // 0..127
        int kq  = idx & 15;          // 0..15
        float4 v = *reinterpret_cast<const float4*>(
            &input[(size_t)(row0 + row) * 64 + kq * 4]);
        Xs[kq * 4 + 0][row] = v.x;
        Xs[kq * 4 + 1][row] = v.y;
        Xs[kq * 4 + 2][row] = v.z;
        Xs[kq * 4 + 3][row] = v.w;
    }
    __syncthreads();

    // ---- sx per row ----
    if (t < 128) {
        float s = 0.f;
#pragma unroll 8
        for (int k = 0; k < 64; ++k) { float x = Xs[k][t]; s = fmaf(x, x, s); }
        sxs[t] = s;
    }

    float bestd[8], sx[8];
    int   bestj[8];
#pragma unroll
    for (int r = 0; r < 8; ++r) { bestd[r] = INFINITY; bestj[r] = 0; }

    for (int chunk = 0; chunk < 4; ++chunk) {
        const int ccb = chunk * 128;
        __syncthreads();   // prev k-loop done reading Es (also fences sxs/Xs)
#pragma unroll
        for (int ph = 0; ph < 8; ++ph) {
            int idx = ph * 256 + t;  // 0..2047
            int k   = idx >> 5;      // 0..63
            int cq  = idx & 31;      // 0..31
            float4 v = *reinterpret_cast<const float4*>(
                &embed[k * N_EMBED + ccb + cq * 4]);
            // XOR swizzle: block base c=cq*4 -> c ^ (bit5(c)*4); bit5(c) = (cq>>3)&1
            *reinterpret_cast<float4*>(&Es[k][(cq * 4) ^ (((cq >> 3) & 1) * 4)]) = v;
        }
        __syncthreads();
        if (chunk == 0) {
#pragma unroll
            for (int r = 0; r < 8; ++r) sx[r] = sxs[tr * 8 + r];
        }

        float acc[8][8];
#pragma unroll
        for (int r = 0; r < 8; ++r)
#pragma unroll
            for (int c = 0; c < 8; ++c) acc[r][c] = 0.f;

#pragma unroll 2
        for (int k = 0; k < 64; ++k) {
            float a[8], b[8];
            *reinterpret_cast<float4*>(&a[0]) = *reinterpret_cast<const float4*>(&Xs[k][tr * 8]);
            *reinterpret_cast<float4*>(&a[4]) = *reinterpret_cast<const float4*>(&Xs[k][tr * 8 + 4]);
            *reinterpret_cast<float4*>(&b[0]) = *reinterpret_cast<const float4*>(&Es[k][(tc * 8) ^ bx]);
            *reinterpret_cast<float4*>(&b[4]) = *reinterpret_cast<const float4*>(&Es[k][(tc * 8 + 4) ^ bx]);
#pragma unroll
            for (int r = 0; r < 8; ++r)
#pragma unroll
                for (int c = 0; c < 8; ++c)
                    acc[r][c] = fmaf(a[r], b[c], acc[r][c]);
        }

        // finalize this chunk: scan cols in increasing j (first-wins ties)
#pragma unroll
        for (int c = 0; c < 8; ++c) {
            int j = ccb + tc * 8 + c;
            float sej = se[j];
#pragma unroll
            for (int r = 0; r < 8; ++r) {
                float d = (sx[r] - 2.f * acc[r][c]) + sej;
                if (d < bestd[r]) { bestd[r] = d; bestj[r] = j; }
            }
        }
    }

    // ---- cross-thread argmin reduce (lexicographic (d, j) == global first-min) ----
    __syncthreads();
    float* rd = &Es[0][0];                 // [128][17]
    int*   rj = (int*)(rd + 128 * 17);     // [128][17]
#pragma unroll
    for (int r = 0; r < 8; ++r) {
        rd[(tr * 8 + r) * 17 + tc] = bestd[r];
        rj[(tr * 8 + r) * 17 + tc] = bestj[r];
    }
    __syncthreads();
    if (t < 128) {
        float bd = rd[t * 17 + 0];
        int   bj = rj[t * 17 + 0];
#pragma unroll
        for (int w = 1; w < 16; ++w) {
            float dw = rd[t * 17 + w];
            int   jw = rj[t * 17 + w];
            if (dw < bd || (dw == bd && jw < bj)) { bd = dw; bj = jw; }
        }
        out_ind[row0 + t] = (float)bj;
        ind[row0 + t]     = bj;
    }
}

// ---------- post: fused quantize + diff + segment-sum (LDS) + atomic flush ----------
__launch_bounds__(512, 1)
__global__ void vq_post(const float* __restrict__ input,
                        const float* __restrict__ embed,
                        const float* __restrict__ embed_t,
                        const int* __restrict__ ind,
                        float* __restrict__ out_q,
                        float* __restrict__ esum,
                        float* __restrict__ counts,
                        double* __restrict__ diff_acc,
                        int have_et) {
    __shared__ float lesum[DIM * N_EMBED];   // 128 KB
    __shared__ float lcount[N_EMBED];
    __shared__ float wsum[8];
    const int t = threadIdx.x;

    float4* l4 = reinterpret_cast<float4*>(lesum);
#pragma unroll
    for (int i = 0; i < 16; ++i) l4[t + i * 512] = float4{0.f, 0.f, 0.f, 0.f};
    lcount[t] = 0.f;
    __syncthreads();

    const int row = blockIdx.x * 512 + t;    // one row per thread
    const int j = ind[row];
    atomicAdd(&lcount[j], 1.0f);
    const float* rp = input + (size_t)row * DIM;
    float* oq = out_q + (size_t)row * DIM;
    float dsum = 0.f;

    if (have_et) {
        const float* qp = embed_t + (size_t)j * DIM;
#pragma unroll
        for (int d = 0; d < DIM; d += 4) {
            float4 v = *reinterpret_cast<const float4*>(rp + d);
            float4 q = *reinterpret_cast<const float4*>(qp + d);
            float t0 = q.x - v.x, t1 = q.y - v.y, t2 = q.z - v.z, t3 = q.w - v.w;
            float4 o;
            o.x = v.x + t0; o.y = v.y + t1; o.z = v.z + t2; o.w = v.w + t3;
            *reinterpret_cast<float4*>(oq + d) = o;
            dsum = fmaf(t0, t0, dsum); dsum = fmaf(t1, t1, dsum);
            dsum = fmaf(t2, t2, dsum); dsum = fmaf(t3, t3, dsum);
            atomicAdd(&lesum[(d + 0) * N_EMBED + j], v.x);
            atomicAdd(&lesum[(d + 1) * N_EMBED + j], v.y);
            atomicAdd(&lesum[(d + 2) * N_EMBED + j], v.z);
            atomicAdd(&lesum[(d + 3) * N_EMBED + j], v.w);
        }
    } else {
#pragma unroll
        for (int d = 0; d < DIM; d += 4) {
            float4 v = *reinterpret_cast<const float4*>(rp + d);
            float q0 = embed[(d + 0) * N_EMBED + j];
            float q1 = embed[(d + 1) * N_EMBED + j];
            float q2 = embed[(d + 2) * N_EMBED + j];
            float q3 = embed[(d + 3) * N_EMBED + j];
            float t0 = q0 - v.x, t1 = q1 - v.y, t2 = q2 - v.z, t3 = q3 - v.w;
            float4 o;
            o.x = v.x + t0; o.y = v.y + t1; o.z = v.z + t2; o.w = v.w + t3;
            *reinterpret_cast<float4*>(oq + d) = o;
            dsum = fmaf(t0, t0, dsum); dsum = fmaf(t1, t1, dsum);
            dsum = fmaf(t2, t2, dsum); dsum = fmaf(t3, t3, dsum);
            atomicAdd(&lesum[(d + 0) * N_EMBED + j], v.x);
            atomicAdd(&lesum[(d + 1) * N_EMBED + j], v.y);
            atomicAdd(&lesum[(d + 2) * N_EMBED + j], v.z);
            atomicAdd(&lesum[(d + 3) * N_EMBED + j], v.w);
        }
    }
    __syncthreads();

    // coalesced atomic flush into global esum / counts
    for (int i = t; i < DIM * N_EMBED; i += 512) {
        float v = lesum[i];
        if (v != 0.f) atomicAdd(&esum[i], v);
    }
    {
        float v = lcount[t];
        if (v != 0.f) atomicAdd(&counts[t], v);
    }

    // diff: wave -> block reduce, one f64 atomic per block
    for (int off = 32; off > 0; off >>= 1) dsum += __shfl_down(dsum, off, 64);
    int lane = t & 63, wid = t >> 6;
    if (lane == 0) wsum[wid] = dsum;
    __syncthreads();
    if (t == 0) {
        float b = 0.f;
#pragma unroll
        for (int w = 0; w < 8; ++w) b += wsum[w];
        atomicAdd(diff_acc, (double)b);
    }
}

// ---------- finalize A: new_cluster_size + n ----------
__global__ void fin_a(const float* __restrict__ cluster_size,
                      const float* __restrict__ counts,
                      float* __restrict__ out_ncs,
                      float* __restrict__ nstore) {
    int t = threadIdx.x;  // 512 threads, 1 block
    float ncs = cluster_size[t] * 0.99f + 0.01f * counts[t];
    out_ncs[t] = ncs;
    __shared__ float red[512];
    red[t] = ncs;
    __syncthreads();
    for (int s = 256; s > 0; s >>= 1) {
        if (t < s) red[t] += red[t + s];
        __syncthreads();
    }
    if (t == 0) nstore[0] = red[0];
}

// ---------- finalize B: new_embed_avg + new_embed + diff, fully coalesced ----------
__global__ void fin_b(const float* __restrict__ embed_avg,
                      const float* __restrict__ esum,
                      const float* __restrict__ out_ncs,
                      const float* __restrict__ nstore,
                      const double* __restrict__ diff_acc,
                      float* __restrict__ out_ne,
                      float* __restrict__ out_nea,
                      float* __restrict__ out_diff) {
    int e = blockIdx.x * 512 + threadIdx.x;   // 64 blocks -> 32768
    const float EPSF = 1e-5f;
    float n = nstore[0];
    int j = e & (N_EMBED - 1);
    float ncs = out_ncs[j];
    float cs = (ncs + EPSF) / (n + 512.0f * EPSF) * n;
    float es = embed_avg[e] * 0.99f + 0.01f * esum[e];
    out_nea[e] = es;
    out_ne[e] = es / cs;
    if (e == 0) out_diff[0] = (float)(*diff_acc * (1.0 / 8388608.0));
}

extern "C" void kernel_launch(void* const* d_in, const int* in_sizes, int n_in,
                              void* d_out, int out_size, void* d_ws, size_t ws_size,
                              hipStream_t stream) {
    const float* input        = (const float*)d_in[0];
    const float* embed        = (const float*)d_in[1];
    const float* cluster_size = (const float*)d_in[2];
    const float* embed_avg    = (const float*)d_in[3];

    float* out_q    = (float*)d_out;          // 8388608 floats
    float* out_diff = out_q + 8388608;        // 1
    float* out_ind  = out_diff + 1;           // 131072
    float* out_ne   = out_ind + 131072;       // 32768
    float* out_ncs  = out_ne + 32768;         // 512
    float* out_nea  = out_ncs + 512;          // 32768

    // ws layout
    char*   ws       = (char*)d_ws;
    double* diff_acc = (double*)ws;                              // [0,8)
    float*  nstore   = (float*)(ws + 64);                        // 1 f32
    float*  counts   = (float*)(ws + 256);                       // 512 f32
    float*  se       = (float*)(ws + 4096);                      // 512 f32
    int*    ind      = (int*)(ws + 8192);                        // 131072 i32
    float*  esum     = (float*)(ws + 8192 + 524288);             // 32768 f32
    float*  embed_t  = (float*)(ws + 8192 + 524288 + 131072);    // 32768 f32 (optional)

    const size_t need_et = 8192 + 524288 + 131072 + 131072;
    const int have_et = (ws_size >= need_et) ? 1 : 0;

    hipMemsetAsync(ws, 0, 4096, stream);                   // diff_acc + nstore + counts
    hipMemsetAsync(ws + 8192 + 524288, 0, 131072, stream); // esum
    prep_kernel<<<2, 256, 0, stream>>>(embed, se, embed_t, have_et);
    vq_assign<<<1024, 256, 0, stream>>>(input, embed, se, out_ind, ind);
    vq_post<<<256, 512, 0, stream>>>(input, embed, embed_t, ind, out_q, esum, counts,
                                     diff_acc, have_et);
    fin_a<<<1, 512, 0, stream>>>(cluster_size, counts, out_ncs, nstore);
    fin_b<<<64, 512, 0, stream>>>(embed_avg, esum, out_ncs, nstore, diff_acc,
                                  out_ne, out_nea, out_diff);
}